// Round 1
// baseline (51.720 us; speedup 1.0000x reference)
//
#include <hip/hip_runtime.h>
#include <math.h>

#define LOG_SQRT_2PI 0.9189385332046727f

__global__ void zero_ws(float* ws) {
    if (threadIdx.x == 0 && blockIdx.x == 0) ws[0] = 0.0f;
}

// One thread per batch row: branchy expected-mu + 7-element NLL sum,
// block-reduce, one atomicAdd per block. Total data ~460 KB -> negligible.
__global__ __launch_bounds__(256) void prior_kernel(
        const float* __restrict__ pred,
        const float* __restrict__ sigma,
        float* __restrict__ ws, int B) {
    int b = blockIdx.x * blockDim.x + threadIdx.x;
    float s = 0.0f;
    if (b < B) {
        const float* p  = pred  + (size_t)b * 7;
        const float* sg = sigma + (size_t)b * 7;
        float O2 = p[0], N2 = p[1], H2 = p[2], CO2 = p[3];
        float H2O = p[4], CH4 = p[5], NH3 = p[6];

        float H = 2.f*H2 + 2.f*H2O + 3.f*NH3 + 4.f*CH4;
        float C = CO2 + CH4;
        float O = 2.f*O2 + 2.f*CO2 + H2O;
        float N = 2.f*N2 + NH3;

        float mu0=0.f, mu1=0.f, mu2=0.f, mu3=0.f, mu4=0.f, mu5=0.f, mu6=0.f;

        bool condA = (H > 2.f*O + 4.f*C);
        if (condA) {
            if (3.f*N < H - 2.f*O - 4.f*C) {
                // branch A1: D = H - N - 2C
                float D = H - N - 2.f*C;
                mu2 = (H - 2.f*O - 4.f*C - 3.f*N) / D;
                mu4 = (2.f*O) / D;
                mu5 = (2.f*C) / D;
                mu6 = (2.f*N) / D;
            } else {
                // branch A2: D = H + 2C + 3N + 4O
                float D = H + 2.f*C + 3.f*N + 4.f*O;
                mu1 = (3.f*N + 4.f*C + 2.f*O - H) / D;
                mu4 = (6.f*O) / D;
                mu5 = (6.f*C) / D;
                mu6 = (2.f*H - 8.f*C - 4.f*O) / D;
            }
        } else if (2.f*O > H + 4.f*C) {
            // branch B: D = H + 2O + 2N
            float D = H + 2.f*O + 2.f*N;
            mu0 = (2.f*O - H - 4.f*C) / D;
            mu1 = (2.f*N) / D;
            mu3 = (4.f*C) / D;
            mu4 = (2.f*H) / D;
        } else if (fabsf(H + C + O + N - 1.0f) < 1e-3f) {
            // branch C: D1 = H + 2O + 2N, D2 = 2H + 4O + 4N
            float D1 = H + 2.f*O + 2.f*N;
            float D2 = 2.f*H + 4.f*O + 4.f*N;
            mu1 = (2.f*N) / D1;
            mu3 = (2.f*O + 4.f*C - H) / D2;
            mu4 = (H + 2.f*O - 4.f*C) / D1;
            mu5 = (H - 2.f*O + 4.f*C) / D2;
        }

        float mu[7] = {mu0, mu1, mu2, mu3, mu4, mu5, mu6};
        #pragma unroll
        for (int i = 0; i < 7; ++i) {
            float d = p[i] - mu[i];
            float sgi = sg[i];
            s += LOG_SQRT_2PI + logf(sgi) + d * d / (2.0f * sgi * sgi);
        }
    }

    // wave64 shuffle reduce, then cross-wave via LDS
    #pragma unroll
    for (int off = 32; off > 0; off >>= 1) s += __shfl_down(s, off, 64);
    __shared__ float wsum[4];
    int lane = threadIdx.x & 63, w = threadIdx.x >> 6;
    if (lane == 0) wsum[w] = s;
    __syncthreads();
    if (threadIdx.x == 0) {
        atomicAdd(ws, wsum[0] + wsum[1] + wsum[2] + wsum[3]);
    }
}

// One block per batch row; float4 streaming of both spectra.
__global__ __launch_bounds__(256) void loss_kernel(
        const float* __restrict__ yReal,
        const float* __restrict__ ySim,
        const float* __restrict__ ws,
        float* __restrict__ out, int S, float inv_b) {
    int b = blockIdx.x;
    const float4* yr = (const float4*)(yReal + (size_t)b * S);
    const float4* ys = (const float4*)(ySim  + (size_t)b * S);
    int n4 = S >> 2;

    float s = 0.0f;
    for (int i = threadIdx.x; i < n4; i += blockDim.x) {
        float4 a = yr[i];
        float4 c = ys[i];
        float d0 = a.x - c.x, d1 = a.y - c.y;
        float d2 = a.z - c.z, d3 = a.w - c.w;
        s += d0*d0 + d1*d1 + d2*d2 + d3*d3;
    }

    #pragma unroll
    for (int off = 32; off > 0; off >>= 1) s += __shfl_down(s, off, 64);
    __shared__ float wsum[4];
    int lane = threadIdx.x & 63, w = threadIdx.x >> 6;
    if (lane == 0) wsum[w] = s;
    __syncthreads();
    if (threadIdx.x == 0) {
        float mse = (wsum[0] + wsum[1] + wsum[2] + wsum[3]) / (float)S;
        // likelihood = mse / (2*0.1^2) = mse * 50 ; prior = ws[0] / B
        out[b] = mse * 50.0f + ws[0] * inv_b;
    }
}

extern "C" void kernel_launch(void* const* d_in, const int* in_sizes, int n_in,
                              void* d_out, int out_size, void* d_ws, size_t ws_size,
                              hipStream_t stream) {
    const float* pred  = (const float*)d_in[0];
    const float* sigma = (const float*)d_in[1];
    const float* yReal = (const float*)d_in[2];
    const float* ySim  = (const float*)d_in[3];
    float* out = (float*)d_out;
    float* ws  = (float*)d_ws;

    int B = in_sizes[0] / 7;
    int S = in_sizes[2] / B;

    zero_ws<<<1, 64, 0, stream>>>(ws);
    int pb = (B + 255) / 256;
    prior_kernel<<<pb, 256, 0, stream>>>(pred, sigma, ws, B);
    loss_kernel<<<B, 256, 0, stream>>>(yReal, ySim, ws, out, S, 1.0f / (float)B);
}

// Round 2
// 47.323 us; speedup vs baseline: 1.0929x; 1.0929x over previous
//
#include <hip/hip_runtime.h>
#include <math.h>

#define LOG_SQRT_2PI 0.9189385332046727f

// ---------------------------------------------------------------------------
// Prior: one partial per block, NO atomics, NO pre-zeroed accumulator.
// Each thread handles row(s) b = blk*256 + tid (+ stride). Branchy 7-element
// expected-mu + NLL row sum, block-reduce -> ws[blk]. ~460 KB total, ~2-3 us.
// ---------------------------------------------------------------------------
__global__ __launch_bounds__(256) void prior_partials(
        const float* __restrict__ pred,
        const float* __restrict__ sigma,
        float* __restrict__ ws, int B, int pb) {
    float s = 0.0f;
    for (int b = blockIdx.x * 256 + threadIdx.x; b < B; b += pb * 256) {
        const float* p  = pred  + (size_t)b * 7;
        const float* sg = sigma + (size_t)b * 7;
        float O2 = p[0], N2 = p[1], H2 = p[2], CO2 = p[3];
        float H2O = p[4], CH4 = p[5], NH3 = p[6];

        float H = 2.f*H2 + 2.f*H2O + 3.f*NH3 + 4.f*CH4;
        float C = CO2 + CH4;
        float O = 2.f*O2 + 2.f*CO2 + H2O;
        float N = 2.f*N2 + NH3;

        float mu0=0.f, mu1=0.f, mu2=0.f, mu3=0.f, mu4=0.f, mu5=0.f, mu6=0.f;

        bool condA = (H > 2.f*O + 4.f*C);
        if (condA) {
            if (3.f*N < H - 2.f*O - 4.f*C) {
                float D = H - N - 2.f*C;                 // branch A1
                mu2 = (H - 2.f*O - 4.f*C - 3.f*N) / D;
                mu4 = (2.f*O) / D;
                mu5 = (2.f*C) / D;
                mu6 = (2.f*N) / D;
            } else {
                float D = H + 2.f*C + 3.f*N + 4.f*O;    // branch A2
                mu1 = (3.f*N + 4.f*C + 2.f*O - H) / D;
                mu4 = (6.f*O) / D;
                mu5 = (6.f*C) / D;
                mu6 = (2.f*H - 8.f*C - 4.f*O) / D;
            }
        } else if (2.f*O > H + 4.f*C) {
            float D = H + 2.f*O + 2.f*N;                // branch B
            mu0 = (2.f*O - H - 4.f*C) / D;
            mu1 = (2.f*N) / D;
            mu3 = (4.f*C) / D;
            mu4 = (2.f*H) / D;
        } else if (fabsf(H + C + O + N - 1.0f) < 1e-3f) {
            float D1 = H + 2.f*O + 2.f*N;               // branch C
            float D2 = 2.f*H + 4.f*O + 4.f*N;
            mu1 = (2.f*N) / D1;
            mu3 = (2.f*O + 4.f*C - H) / D2;
            mu4 = (H + 2.f*O - 4.f*C) / D1;
            mu5 = (H - 2.f*O + 4.f*C) / D2;
        }

        float mu[7] = {mu0, mu1, mu2, mu3, mu4, mu5, mu6};
        #pragma unroll
        for (int i = 0; i < 7; ++i) {
            float d = p[i] - mu[i];
            float sgi = sg[i];
            s += LOG_SQRT_2PI + logf(sgi) + d * d / (2.0f * sgi * sgi);
        }
    }

    #pragma unroll
    for (int off = 32; off > 0; off >>= 1) s += __shfl_down(s, off, 64);
    __shared__ float wsum[4];
    int lane = threadIdx.x & 63, w = threadIdx.x >> 6;
    if (lane == 0) wsum[w] = s;
    __syncthreads();
    if (threadIdx.x == 0) ws[blockIdx.x] = wsum[0] + wsum[1] + wsum[2] + wsum[3];
}

// ---------------------------------------------------------------------------
// Loss: one 256-thread block per row. Compile-time trip count (NITER) fully
// unrolls the float4 streaming loads. The prior partials (<=256 floats,
// L2-hot) are folded into the same block reduce: thread tid contributes
// s_mse*c_mse + partial[tid]*c_prior, so block-sum == out[b] directly.
// ---------------------------------------------------------------------------
template <int NITER>
__global__ __launch_bounds__(256) void loss_kernel_t(
        const float* __restrict__ yReal,
        const float* __restrict__ ySim,
        const float* __restrict__ partials,
        float* __restrict__ out, int S, float c_mse, float c_prior, int pb) {
    int b = blockIdx.x;
    const float4* yr = (const float4*)(yReal + (size_t)b * S);
    const float4* ys = (const float4*)(ySim  + (size_t)b * S);

    // issue the (tiny, ready) prior-partial load first; hides under streaming
    float u = (threadIdx.x < pb) ? partials[threadIdx.x] * c_prior : 0.0f;

    float s = 0.0f;
    #pragma unroll
    for (int k = 0; k < NITER; ++k) {
        int i = threadIdx.x + k * 256;
        float4 a = yr[i];
        float4 c = ys[i];
        float d0 = a.x - c.x, d1 = a.y - c.y;
        float d2 = a.z - c.z, d3 = a.w - c.w;
        s += d0*d0 + d1*d1 + d2*d2 + d3*d3;
    }
    u += s * c_mse;

    #pragma unroll
    for (int off = 32; off > 0; off >>= 1) u += __shfl_down(u, off, 64);
    __shared__ float wsum[4];
    int lane = threadIdx.x & 63, w = threadIdx.x >> 6;
    if (lane == 0) wsum[w] = u;
    __syncthreads();
    if (threadIdx.x == 0) out[b] = wsum[0] + wsum[1] + wsum[2] + wsum[3];
}

// generic fallback (runtime trip count, handles S not multiple of 1024)
__global__ __launch_bounds__(256) void loss_kernel_g(
        const float* __restrict__ yReal,
        const float* __restrict__ ySim,
        const float* __restrict__ partials,
        float* __restrict__ out, int S, float c_mse, float c_prior, int pb) {
    int b = blockIdx.x;
    const float* yr = yReal + (size_t)b * S;
    const float* ys = ySim  + (size_t)b * S;

    float u = (threadIdx.x < pb) ? partials[threadIdx.x] * c_prior : 0.0f;

    float s = 0.0f;
    int n4 = S >> 2;
    const float4* yr4 = (const float4*)yr;
    const float4* ys4 = (const float4*)ys;
    for (int i = threadIdx.x; i < n4; i += 256) {
        float4 a = yr4[i];
        float4 c = ys4[i];
        float d0 = a.x - c.x, d1 = a.y - c.y;
        float d2 = a.z - c.z, d3 = a.w - c.w;
        s += d0*d0 + d1*d1 + d2*d2 + d3*d3;
    }
    for (int i = (n4 << 2) + threadIdx.x; i < S; i += 256) {
        float d = yr[i] - ys[i];
        s += d * d;
    }
    u += s * c_mse;

    #pragma unroll
    for (int off = 32; off > 0; off >>= 1) u += __shfl_down(u, off, 64);
    __shared__ float wsum[4];
    int lane = threadIdx.x & 63, w = threadIdx.x >> 6;
    if (lane == 0) wsum[w] = u;
    __syncthreads();
    if (threadIdx.x == 0) out[b] = wsum[0] + wsum[1] + wsum[2] + wsum[3];
}

extern "C" void kernel_launch(void* const* d_in, const int* in_sizes, int n_in,
                              void* d_out, int out_size, void* d_ws, size_t ws_size,
                              hipStream_t stream) {
    const float* pred  = (const float*)d_in[0];
    const float* sigma = (const float*)d_in[1];
    const float* yReal = (const float*)d_in[2];
    const float* ySim  = (const float*)d_in[3];
    float* out = (float*)d_out;
    float* ws  = (float*)d_ws;

    int B = in_sizes[0] / 7;
    int S = in_sizes[2] / B;

    int pb = (B + 255) / 256;
    if (pb > 256) pb = 256;   // loss folds partials via tid<pb, so cap at 256

    prior_partials<<<pb, 256, 0, stream>>>(pred, sigma, ws, B, pb);

    float c_mse   = 50.0f / (float)S;   // (1/S)*(1/(2*0.1^2))
    float c_prior = 1.0f / (float)B;

    if ((S & 3) == 0 && (S >> 2) == 1024) {
        loss_kernel_t<4><<<B, 256, 0, stream>>>(yReal, ySim, ws, out, S, c_mse, c_prior, pb);
    } else if ((S & 3) == 0 && (S >> 2) == 2048) {
        loss_kernel_t<8><<<B, 256, 0, stream>>>(yReal, ySim, ws, out, S, c_mse, c_prior, pb);
    } else {
        loss_kernel_g<<<B, 256, 0, stream>>>(yReal, ySim, ws, out, S, c_mse, c_prior, pb);
    }
}